// Round 6
// baseline (590.341 us; speedup 1.0000x reference)
//
#include <hip/hip_runtime.h>
#include <math.h>

// approxmatch EMD (Fan et al.) — b=8, n=m=2048, f32.
// R6: B-pass merged into the row kernels via a second "scatter" sweep.
// Schedule (22 dispatches, 11 fat + 11 tiny):
//   zero | A0(2-sweep) | 10 x { thin_t ; CA_t (t<9) or C9 }
// Level t: kk_t = -4^(7-t)*L2E (t<=8), kk_9 = 0.
//   A: f_i = remL_i / (1e-9 + sum_j e(kk)*R_j)
//   B: sigma_j = sum_i f_i e(kk);  colsum = R_j*sigma_j;
//      rr=min(R/(1e-9+colsum),1); c=R*rr; R' = max(R-colsum*rr,0)   [thin]
//   C: t_i = sum_j c e; u_i = sum_j c e sqrt(d2);
//      remL' = max(remL - f t_i, 0); cost += f u_i
// Fat CA_t (t<8): one exp e1=exp2(kk_{t+1} d2) serves C (e1^4), A (e1) and
// the NEXT level's B scatter (f'·e1, sweep 2). sqrt(d2)=sqrt(|t|)/sqrt(|kp|)
// with the constant hoisted. Column partials: LDS ds_add (waves staggered)
// -> one global atomicAdd per (block,j) into double-buffered sigma.

#define NPTS 2048
#define BLOCK 256
#define RPW 4
#define RPB 16            // rows per block -> 128 blocks/batch, 1024 total
#define L2E 1.4426950408889634f

__device__ __forceinline__ float xreduce(float v) {
#pragma unroll
    for (int off = 1; off < 64; off <<= 1) v += __shfl_xor(v, off, 64);
    return v;
}
__device__ __forceinline__ float fexp2(float x) { return __builtin_amdgcn_exp2f(x); }
__device__ __forceinline__ float fsqrt(float x) { return __builtin_amdgcn_sqrtf(x); }

__global__ void k_zero(float* __restrict__ sig2, float* __restrict__ out,
                       int nsig, int nout) {
    int i = blockIdx.x * BLOCK + threadIdx.x;
    if (i < nsig) sig2[i] = 0.f;
    if (i < nout) out[i] = 0.f;
}

// Level-0 row pass (remL==multiL, remR==multiR): f + scatter sigma. Also
// packs this block's 16 rows/cols into float4 arrays for later kernels.
__global__ __launch_bounds__(BLOCK, 4) void k_A0(
    const float* __restrict__ xyz1, const float* __restrict__ xyz2,
    float4* __restrict__ p1w, float4* __restrict__ p2w,
    float* __restrict__ f_g, float* __restrict__ sig,
    float kk, float multiL, float multiR)
{
    __shared__ float sx[NPTS], sy[NPTS], sz[NPTS], sm[NPTS];
    const int row0 = blockIdx.x * RPB;
    const int batch = row0 >> 11;
    const int rloc = row0 & 2047;
    const float* g1 = xyz1 + (size_t)batch * NPTS * 3;
    const float* g2 = xyz2 + (size_t)batch * NPTS * 3;
    if (threadIdx.x < RPB) {
        int i = rloc + threadIdx.x;
        p1w[((size_t)batch << 11) + i] = make_float4(g1[3*i], g1[3*i+1], g1[3*i+2], 0.f);
    } else if (threadIdx.x < 2 * RPB) {
        int i = rloc + threadIdx.x - RPB;
        p2w[((size_t)batch << 11) + i] = make_float4(g2[3*i], g2[3*i+1], g2[3*i+2], 0.f);
    }
    for (int j = threadIdx.x; j < NPTS; j += BLOCK) {
        sx[j] = g2[3*j]; sy[j] = g2[3*j+1]; sz[j] = g2[3*j+2];
        sm[j] = 0.f;
    }
    __syncthreads();
    const int lane = threadIdx.x & 63;
    const int wave = threadIdx.x >> 6;
    const int r0 = row0 + wave * RPW;
    float pa[RPW], pxp[RPW], pyp[RPW], pzp[RPW], acc[RPW];
#pragma unroll
    for (int r = 0; r < RPW; ++r) {
        const float* p = g1 + 3 * (rloc + wave * RPW + r);
        float x = p[0], y = p[1], z = p[2];
        pa[r] = kk * (x*x + y*y + z*z);
        pxp[r] = -2.f*kk*x; pyp[r] = -2.f*kk*y; pzp[r] = -2.f*kk*z;
        acc[r] = 0.f;
    }
    for (int j = lane; j < NPTS; j += 64) {
        float qx = sx[j], qy = sy[j], qz = sz[j];
        float qb = kk * fmaf(qx, qx, fmaf(qy, qy, qz * qz));
#pragma unroll
        for (int r = 0; r < RPW; ++r) {
            float t = fmaf(pxp[r], qx, fmaf(pyp[r], qy, fmaf(pzp[r], qz, pa[r] + qb)));
            acc[r] += fexp2(t);
        }
    }
    float fp[RPW];
#pragma unroll
    for (int r = 0; r < RPW; ++r) {
        float s = multiR * xreduce(acc[r]);
        fp[r] = multiL / (1e-9f + s);
        if (lane == 0) f_g[r0 + r] = fp[r];
    }
    // sweep 2: sigma_j += sum_r fp_r * e(kk)  (waves staggered by 512)
    for (int it = 0; it < NPTS / 64; ++it) {
        int j = (wave * 512 + it * 64 + lane) & 2047;
        float qx = sx[j], qy = sy[j], qz = sz[j];
        float qb = kk * fmaf(qx, qx, fmaf(qy, qy, qz * qz));
        float part = 0.f;
#pragma unroll
        for (int r = 0; r < RPW; ++r) {
            float t = fmaf(pxp[r], qx, fmaf(pyp[r], qy, fmaf(pzp[r], qz, pa[r] + qb)));
            part = fmaf(fp[r], fexp2(t), part);
        }
        atomicAdd(&sm[j], part);
    }
    __syncthreads();
    float* sg = sig + ((size_t)batch << 11);
    for (int j = threadIdx.x; j < NPTS; j += BLOCK)
        atomicAdd(&sg[j], sm[j]);
}

// thin column finish: c_j, remR' from sigma; re-zero sigma buffer.
template <bool FIRST>
__global__ void k_thin(float* __restrict__ sig, float* __restrict__ remR,
                       float* __restrict__ c_g, float multiR)
{
    int idx = blockIdx.x * BLOCK + threadIdx.x;
    float s = sig[idx];
    sig[idx] = 0.f;
    float R = FIRST ? multiR : remR[idx];
    float colsum = R * s;
    float rr = fminf(R / (1e-9f + colsum), 1.0f);
    c_g[idx] = R * rr;
    remR[idx] = fmaxf(R - colsum * rr, 0.f);
}

// Fat row pass: C_t + A_{t+1} + scatter of B_{t+1}'s sigma.
// MODE 1 (t<8): kp = kk_t/4 = kk_{t+1}; C-weight = e1^4; aA += rw*e1;
//               sweep2 partial = f'*e1.
// MODE 2 (t=8): kp = kk_8; C-weight = e1; aA = sum rw (next level kk=0);
//               sweep2 partial = sum_r f'_r (constant).
template <int MODE, bool FIRSTC>
__global__ __launch_bounds__(BLOCK, 4) void k_CA(
    const float4* __restrict__ p1w, const float4* __restrict__ p2w,
    float* __restrict__ f_g, const float* __restrict__ c_g,
    const float* __restrict__ remR, float* __restrict__ remL,
    float* __restrict__ costrow, float* __restrict__ sig,
    float kp, float rsqkp, float multiL)
{
    __shared__ float sx[NPTS], sy[NPTS], sz[NPTS], sc[NPTS], sr[NPTS];
    const int row0 = blockIdx.x * RPB;
    const int batch = row0 >> 11;
    const float4* P2 = p2w + ((size_t)batch << 11);
    const float* C = c_g + ((size_t)batch << 11);
    const float* R = remR + ((size_t)batch << 11);
    for (int j = threadIdx.x; j < NPTS; j += BLOCK) {
        float4 q = P2[j];
        sx[j] = q.x; sy[j] = q.y; sz[j] = q.z; sc[j] = C[j]; sr[j] = R[j];
    }
    __syncthreads();
    const int lane = threadIdx.x & 63;
    const int wave = threadIdx.x >> 6;
    const int r0 = row0 + wave * RPW;
    float pa[RPW], pxp[RPW], pyp[RPW], pzp[RPW], fi[RPW];
    float aT[RPW], aU[RPW], aA[RPW], aAs = 0.f;
#pragma unroll
    for (int r = 0; r < RPW; ++r) {
        float4 q = p1w[r0 + r];
        pa[r] = kp * (q.x*q.x + q.y*q.y + q.z*q.z);
        pxp[r] = -2.f*kp*q.x; pyp[r] = -2.f*kp*q.y; pzp[r] = -2.f*kp*q.z;
        fi[r] = f_g[r0 + r];
        aT[r] = 0.f; aU[r] = 0.f; aA[r] = 0.f;
    }
    for (int j = lane; j < NPTS; j += 64) {
        float qx = sx[j], qy = sy[j], qz = sz[j], cw = sc[j], rw = sr[j];
        float qb = kp * fmaf(qx, qx, fmaf(qy, qy, qz * qz));
        if (MODE == 2) aAs += rw;
#pragma unroll
        for (int r = 0; r < RPW; ++r) {
            float t = fmaf(pxp[r], qx, fmaf(pyp[r], qy, fmaf(pzp[r], qz, pa[r] + qb)));
            float e1 = fexp2(t);
            float eC;
            if (MODE == 1) { float e2 = e1 * e1; eC = cw * (e2 * e2); }
            else           { eC = cw * e1; }
            aT[r] += eC;
            aU[r] = fmaf(eC, fsqrt(fabsf(t)), aU[r]);   // sqrt(d2)=sqrt(|t|)*rsqkp
            if (MODE == 1) aA[r] = fmaf(rw, e1, aA[r]);
        }
    }
    float aas = (MODE == 2) ? xreduce(aAs) : 0.f;
    float fp[RPW];
#pragma unroll
    for (int r = 0; r < RPW; ++r) {
        float tt = xreduce(aT[r]);
        float uu = xreduce(aU[r]) * rsqkp;
        float aa = (MODE == 1) ? xreduce(aA[r]) : aas;
        int gi = r0 + r;
        float rl0 = FIRSTC ? multiL : remL[gi];
        float rl = fmaxf(rl0 - fi[r] * tt, 0.f);
        fp[r] = rl / (1e-9f + aa);
        if (lane == 0) {
            costrow[gi] = (FIRSTC ? 0.f : costrow[gi]) + fi[r] * uu;
            remL[gi] = rl;
            f_g[gi] = fp[r];
        }
    }
    // ---- sweep 2: scatter next level's sigma ----
    __syncthreads();
    for (int j = threadIdx.x; j < NPTS; j += BLOCK) sc[j] = 0.f;
    __syncthreads();
    if (MODE == 1) {
        for (int it = 0; it < NPTS / 64; ++it) {
            int j = (wave * 512 + it * 64 + lane) & 2047;
            float qx = sx[j], qy = sy[j], qz = sz[j];
            float qb = kp * fmaf(qx, qx, fmaf(qy, qy, qz * qz));
            float part = 0.f;
#pragma unroll
            for (int r = 0; r < RPW; ++r) {
                float t = fmaf(pxp[r], qx, fmaf(pyp[r], qy, fmaf(pzp[r], qz, pa[r] + qb)));
                part = fmaf(fp[r], fexp2(t), part);
            }
            atomicAdd(&sc[j], part);
        }
    } else {
        if (lane == 0) atomicAdd(&sc[0], fp[0] + fp[1] + fp[2] + fp[3]);
    }
    __syncthreads();
    float* sg = sig + ((size_t)batch << 11);
    if (MODE == 1) {
        for (int j = threadIdx.x; j < NPTS; j += BLOCK)
            atomicAdd(&sg[j], sc[j]);
    } else {
        float bc = sc[0];
        for (int j = threadIdx.x; j < NPTS; j += BLOCK)
            atomicAdd(&sg[j], bc);
    }
}

// Final level (kk=0): u_i = sum_j c_j sqrt(d2); out[b] += f_i u_i + costrow_i
__global__ __launch_bounds__(BLOCK, 4) void k_C9(
    const float4* __restrict__ p1w, const float4* __restrict__ p2w,
    const float* __restrict__ f_g, const float* __restrict__ c_g,
    const float* __restrict__ costrow, float* __restrict__ out)
{
    __shared__ float sx[NPTS], sy[NPTS], sz[NPTS], sc[NPTS];
    __shared__ float wsum[BLOCK / 64];
    const int row0 = blockIdx.x * RPB;
    const int batch = row0 >> 11;
    const float4* P2 = p2w + ((size_t)batch << 11);
    const float* C = c_g + ((size_t)batch << 11);
    for (int j = threadIdx.x; j < NPTS; j += BLOCK) {
        float4 q = P2[j];
        sx[j] = q.x; sy[j] = q.y; sz[j] = q.z; sc[j] = C[j];
    }
    __syncthreads();
    const int lane = threadIdx.x & 63;
    const int wave = threadIdx.x >> 6;
    const int r0 = row0 + wave * RPW;
    float px[RPW], py[RPW], pz[RPW], aU[RPW];
#pragma unroll
    for (int r = 0; r < RPW; ++r) {
        float4 q = p1w[r0 + r];
        px[r] = q.x; py[r] = q.y; pz[r] = q.z; aU[r] = 0.f;
    }
    for (int j = lane; j < NPTS; j += 64) {
        float qx = sx[j], qy = sy[j], qz = sz[j], cw = sc[j];
#pragma unroll
        for (int r = 0; r < RPW; ++r) {
            float dx = px[r] - qx, dy = py[r] - qy, dz = pz[r] - qz;
            float d2 = fmaf(dx, dx, fmaf(dy, dy, dz * dz));
            aU[r] = fmaf(cw, fsqrt(d2), aU[r]);
        }
    }
    float psum = 0.f;
#pragma unroll
    for (int r = 0; r < RPW; ++r) {
        float uu = xreduce(aU[r]);
        if (lane == 0) psum += costrow[r0 + r] + f_g[r0 + r] * uu;
    }
    if (lane == 0) wsum[wave] = psum;
    __syncthreads();
    if (threadIdx.x == 0)
        atomicAdd(&out[batch], wsum[0] + wsum[1] + wsum[2] + wsum[3]);
}

extern "C" void kernel_launch(void* const* d_in, const int* in_sizes, int n_in,
                              void* d_out, int out_size, void* d_ws, size_t ws_size,
                              hipStream_t stream) {
    const float* xyz1 = (const float*)d_in[0];
    const float* xyz2 = (const float*)d_in[1];
    float* out = (float*)d_out;
    const int b = out_size;                 // 8
    const int n = in_sizes[0] / (3 * b);    // 2048
    const int m = in_sizes[1] / (3 * b);    // 2048
    const int bn = b * n, bm = b * m;

    float4* p1w = (float4*)d_ws;            // bn
    float4* p2w = p1w + bn;                 // bm
    float* remR    = (float*)(p2w + bm);    // bm
    float* f       = remR + bm;             // bn
    float* c       = f + bn;                // bm
    float* remL    = c + bm;                // bn
    float* costrow = remL + bn;             // bn
    float* sig     = costrow + bn;          // 2*bm (double-buffered)

    const float multiL = (float)((m / n > 1) ? (m / n) : 1);
    const float multiR = (float)((n / m > 1) ? (n / m) : 1);

    dim3 blk(BLOCK);
    dim3 gFat(bn / RPB), gThin(bm / BLOCK);

    k_zero<<<dim3((2 * bm + BLOCK - 1) / BLOCK), blk, 0, stream>>>(sig, out, 2 * bm, b);

    const float kk0 = -16384.f * L2E;       // level -4^7
    k_A0<<<gFat, blk, 0, stream>>>(xyz1, xyz2, p1w, p2w, f, sig, kk0, multiL, multiR);

    for (int t = 0; t < 10; ++t) {
        float* sigR = sig + (size_t)(t & 1) * bm;
        float* sigW = sig + (size_t)((t + 1) & 1) * bm;
        if (t == 0) k_thin<true><<<gThin, blk, 0, stream>>>(sigR, remR, c, multiR);
        else        k_thin<false><<<gThin, blk, 0, stream>>>(sigR, remR, c, multiR);

        if (t < 8) {
            const float kk = -exp2f(2.f * (float)(7 - t)) * L2E;  // level_t * log2e
            const float kp = kk * 0.25f;                          // = kk_{t+1}
            const float rsq = 1.f / sqrtf(-kp);
            if (t == 0)
                k_CA<1, true><<<gFat, blk, 0, stream>>>(p1w, p2w, f, c, remR, remL,
                                                        costrow, sigW, kp, rsq, multiL);
            else
                k_CA<1, false><<<gFat, blk, 0, stream>>>(p1w, p2w, f, c, remR, remL,
                                                         costrow, sigW, kp, rsq, multiL);
        } else if (t == 8) {
            const float kp = -0.25f * L2E;                        // kk_8
            const float rsq = 1.f / sqrtf(0.25f * L2E);
            k_CA<2, false><<<gFat, blk, 0, stream>>>(p1w, p2w, f, c, remR, remL,
                                                     costrow, sigW, kp, rsq, multiL);
        } else {
            k_C9<<<gFat, blk, 0, stream>>>(p1w, p2w, f, c, costrow, out);
        }
    }
}

// Round 7
// 310.960 us; speedup vs baseline: 1.8984x; 1.8984x over previous
//
#include <hip/hip_runtime.h>
#include <math.h>

// approxmatch EMD (Fan et al.) — b=8, n=m=2048, f32.
// R7: scalar-broadcast structure. Each lane owns ONE row (or col); the swept
// operand index is WAVE-UNIFORM so the swept stream (points packed as
// (x,y,z,|p|^2) float4 + weight floats) comes in via s_load (SMEM pipe) and
// feeds VALU as SGPR sources. No LDS staging, no per-row shuffle reduce —
// only a NW-partial cross-wave LDS reduce per row at the end.
// Schedule (22 dispatches): prep | A0 | 10 x { B_t ; CA_t or C9 }.
//   A: f_i = remL_i/(1e-9 + sum_j e(kk)R_j)
//   B: s_j = sum_i f_i e(kk); colsum=R s; rr=min(R/(1e-9+colsum),1); c=R rr;
//      R' = max(R-colsum rr,0)
//   C: t_i=sum_j c e; u_i=sum_j c e sqrt(d2); remL'=max(remL-f t,0); cost+=f u
// CA_t fuses C_t with A_{t+1}: one exp e1=exp2(kk_{t+1} d2) serves C (e1^4)
// and A (e1), since level_t = 4*level_{t+1} exactly for t<8.
// Folded exponent: kk*d2 = kk|p|^2 + kk|q|^2 - 2kk(p.q); sqrt(d2) =
// sqrt(|kk*d2|)/sqrt(|kk|) with the constant hoisted out of the loop.

#define NPTS 2048
#define BT 1024
#define NW 16                 // waves per block
#define CHUNK (NPTS / NW)     // 128 swept indices per wave
#define L2E 1.4426950408889634f

__device__ __forceinline__ float fexp2(float x) { return __builtin_amdgcn_exp2f(x); }
__device__ __forceinline__ float fsqrt(float x) { return __builtin_amdgcn_sqrtf(x); }
__device__ __forceinline__ float xreduce(float v) {
#pragma unroll
    for (int off = 1; off < 64; off <<= 1) v += __shfl_xor(v, off, 64);
    return v;
}

// Pack points as (x,y,z,|p|^2); zero the output accumulators.
__global__ void k_prep(const float* __restrict__ xyz1, const float* __restrict__ xyz2,
                       float4* __restrict__ S1, float4* __restrict__ S2,
                       float* __restrict__ out, int bn, int bm, int nout) {
    int i = blockIdx.x * 256 + threadIdx.x;
    if (i < bn) {
        const float* p = xyz1 + 3 * (size_t)i;
        float x = p[0], y = p[1], z = p[2];
        S1[i] = make_float4(x, y, z, x*x + y*y + z*z);
    }
    if (i < bm) {
        const float* p = xyz2 + 3 * (size_t)i;
        float x = p[0], y = p[1], z = p[2];
        S2[i] = make_float4(x, y, z, x*x + y*y + z*z);
    }
    if (i < nout) out[i] = 0.f;
}

// Level-0 rows pass: f_i = multiL / (1e-9 + multiR * sum_j e(kk)).
__global__ __launch_bounds__(BT, 1) void k_A0(
    const float4* __restrict__ S1, const float4* __restrict__ S2,
    float* __restrict__ f_g, float kk, float multiL, float multiR)
{
    __shared__ float red[NW * 64];
    const int row0 = blockIdx.x * 64;
    const int batch = row0 >> 11;
    const int lane = threadIdx.x & 63;
    const int wave = __builtin_amdgcn_readfirstlane(threadIdx.x >> 6);
    const float4* Q = S2 + ((size_t)batch << 11) + wave * CHUNK;
    float4 p = S1[row0 + lane];
    float vkk = kk;
    float pa = kk * p.w, pxp = -2.f*kk*p.x, pyp = -2.f*kk*p.y, pzp = -2.f*kk*p.z;
    float acc = 0.f;
#pragma unroll 8
    for (int j = 0; j < CHUNK; ++j) {
        float4 q = Q[j];                       // uniform -> s_load
        float t = fmaf(pxp, q.x, fmaf(pyp, q.y, fmaf(pzp, q.z, fmaf(vkk, q.w, pa))));
        acc += fexp2(t);
    }
    red[wave * 64 + lane] = acc;
    __syncthreads();
    if (threadIdx.x < 64) {
        float s = 0.f;
#pragma unroll
        for (int w = 0; w < NW; ++w) s += red[w * 64 + threadIdx.x];
        f_g[row0 + threadIdx.x] = multiL / (1e-9f + multiR * s);
    }
}

// Cols pass: lane owns col j; sweep rows i scalarly (S1 + f streams).
template <bool FIRST>
__global__ __launch_bounds__(BT, 1) void k_B(
    const float4* __restrict__ S1, const float4* __restrict__ S2,
    const float* __restrict__ f_g, float* __restrict__ remR,
    float* __restrict__ c_g, float kk, float multiR)
{
    __shared__ float red[NW * 64];
    const int col0 = blockIdx.x * 64;
    const int batch = col0 >> 11;
    const int lane = threadIdx.x & 63;
    const int wave = __builtin_amdgcn_readfirstlane(threadIdx.x >> 6);
    const float4* P = S1 + ((size_t)batch << 11) + wave * CHUNK;
    const float* F = f_g + ((size_t)batch << 11) + wave * CHUNK;
    float4 q = S2[col0 + lane];
    float vkk = kk;
    float ca = kk * q.w, cxp = -2.f*kk*q.x, cyp = -2.f*kk*q.y, czp = -2.f*kk*q.z;
    float acc = 0.f;
#pragma unroll 8
    for (int i = 0; i < CHUNK; ++i) {
        float4 p = P[i];                       // uniform -> s_load
        float fi = F[i];                       // uniform -> s_load
        float t = fmaf(cxp, p.x, fmaf(cyp, p.y, fmaf(czp, p.z, fmaf(vkk, p.w, ca))));
        acc = fmaf(fi, fexp2(t), acc);
    }
    red[wave * 64 + lane] = acc;
    __syncthreads();
    if (threadIdx.x < 64) {
        float s = 0.f;
#pragma unroll
        for (int w = 0; w < NW; ++w) s += red[w * 64 + threadIdx.x];
        int gj = col0 + threadIdx.x;
        float R = FIRST ? multiR : remR[gj];
        float colsum = R * s;
        float rr = fminf(R / (1e-9f + colsum), 1.0f);
        c_g[gj] = R * rr;
        remR[gj] = fmaxf(R - colsum * rr, 0.f);
    }
}

// Rows pass: C_t + fused A_{t+1}.
// MODE 1 (t<8): kp = kk_t/4 = kk_{t+1}; C-weight = e1^4; aA += R_j*e1.
// MODE 2 (t=8): kp = kk_8; C-weight = e1; aA += R_j (next level kk = 0).
template <int MODE, bool FIRSTC>
__global__ __launch_bounds__(BT, 1) void k_CA(
    const float4* __restrict__ S1, const float4* __restrict__ S2,
    float* __restrict__ f_g, const float* __restrict__ c_g,
    const float* __restrict__ remR, float* __restrict__ remL,
    float* __restrict__ costrow, float kp, float rsqkp, float multiL)
{
    __shared__ float redT[NW * 64], redU[NW * 64], redA[NW * 64];
    const int row0 = blockIdx.x * 64;
    const int batch = row0 >> 11;
    const int lane = threadIdx.x & 63;
    const int wave = __builtin_amdgcn_readfirstlane(threadIdx.x >> 6);
    const size_t bb = (size_t)batch << 11;
    const float4* Q = S2 + bb + wave * CHUNK;
    const float* C = c_g + bb + wave * CHUNK;
    const float* R = remR + bb + wave * CHUNK;
    float4 p = S1[row0 + lane];
    float vkp = kp;
    float pa = kp * p.w, pxp = -2.f*kp*p.x, pyp = -2.f*kp*p.y, pzp = -2.f*kp*p.z;
    float aT = 0.f, aU = 0.f, aA = 0.f;
#pragma unroll 4
    for (int j = 0; j < CHUNK; ++j) {
        float4 q = Q[j];                       // uniform -> s_load
        float cw = C[j];                       // uniform -> s_load
        float rw = R[j];                       // uniform -> s_load
        float t = fmaf(pxp, q.x, fmaf(pyp, q.y, fmaf(pzp, q.z, fmaf(vkp, q.w, pa))));
        float e1 = fexp2(t);
        float eC;
        if (MODE == 1) { float e2 = e1 * e1; eC = cw * (e2 * e2); }
        else           { eC = cw * e1; }
        aT += eC;
        aU = fmaf(eC, fsqrt(fabsf(t)), aU);    // sqrt(d2) = sqrt(|t|)*rsqkp
        if (MODE == 1) aA = fmaf(rw, e1, aA);
        else           aA += rw;
    }
    redT[wave * 64 + lane] = aT;
    redU[wave * 64 + lane] = aU;
    redA[wave * 64 + lane] = aA;
    __syncthreads();
    if (threadIdx.x < 64) {
        float tt = 0.f, uu = 0.f, aa = 0.f;
#pragma unroll
        for (int w = 0; w < NW; ++w) {
            tt += redT[w * 64 + threadIdx.x];
            uu += redU[w * 64 + threadIdx.x];
            aa += redA[w * 64 + threadIdx.x];
        }
        int gi = row0 + threadIdx.x;
        float fi = f_g[gi];
        float rl = fmaxf((FIRSTC ? multiL : remL[gi]) - fi * tt, 0.f);
        costrow[gi] = (FIRSTC ? 0.f : costrow[gi]) + fi * uu * rsqkp;
        remL[gi] = rl;
        f_g[gi] = rl / (1e-9f + aa);
    }
}

// Final level (kk=0): u_i = sum_j c_j sqrt(d2); out[batch] += costrow_i + f_i u_i.
__global__ __launch_bounds__(BT, 1) void k_C9(
    const float4* __restrict__ S1, const float4* __restrict__ S2,
    const float* __restrict__ f_g, const float* __restrict__ c_g,
    const float* __restrict__ costrow, float* __restrict__ out)
{
    __shared__ float redU[NW * 64];
    const int row0 = blockIdx.x * 64;
    const int batch = row0 >> 11;
    const int lane = threadIdx.x & 63;
    const int wave = __builtin_amdgcn_readfirstlane(threadIdx.x >> 6);
    const size_t bb = (size_t)batch << 11;
    const float4* Q = S2 + bb + wave * CHUNK;
    const float* C = c_g + bb + wave * CHUNK;
    float4 p = S1[row0 + lane];
    float aU = 0.f;
#pragma unroll 8
    for (int j = 0; j < CHUNK; ++j) {
        float4 q = Q[j];                       // uniform -> s_load
        float cw = C[j];
        float dx = p.x - q.x, dy = p.y - q.y, dz = p.z - q.z;
        float d2 = fmaf(dx, dx, fmaf(dy, dy, dz * dz));
        aU = fmaf(cw, fsqrt(d2), aU);
    }
    redU[wave * 64 + lane] = aU;
    __syncthreads();
    if (threadIdx.x < 64) {
        float uu = 0.f;
#pragma unroll
        for (int w = 0; w < NW; ++w) uu += redU[w * 64 + threadIdx.x];
        int gi = row0 + threadIdx.x;
        float val = costrow[gi] + f_g[gi] * uu;
        float s = xreduce(val);
        if (threadIdx.x == 0) atomicAdd(&out[batch], s);
    }
}

extern "C" void kernel_launch(void* const* d_in, const int* in_sizes, int n_in,
                              void* d_out, int out_size, void* d_ws, size_t ws_size,
                              hipStream_t stream) {
    const float* xyz1 = (const float*)d_in[0];
    const float* xyz2 = (const float*)d_in[1];
    float* out = (float*)d_out;
    const int b = out_size;                 // 8
    const int n = in_sizes[0] / (3 * b);    // 2048
    const int m = in_sizes[1] / (3 * b);    // 2048
    const int bn = b * n, bm = b * m;

    float4* S1 = (float4*)d_ws;             // bn
    float4* S2 = S1 + bn;                   // bm
    float* f       = (float*)(S2 + bm);     // bn
    float* c       = f + bn;                // bm
    float* remR    = c + bm;                // bm
    float* remL    = remR + bm;             // bn
    float* costrow = remL + bn;             // bn

    const float multiL = (float)((m / n > 1) ? (m / n) : 1);
    const float multiR = (float)((n / m > 1) ? (n / m) : 1);

    dim3 blk(BT);
    dim3 gFat(bn / 64);
    const int prepN = (bn > bm ? bn : bm);
    k_prep<<<dim3((prepN + 255) / 256), dim3(256), 0, stream>>>(
        xyz1, xyz2, S1, S2, out, bn, bm, b);

    const float kk0 = -16384.f * L2E;       // level -4^7
    k_A0<<<gFat, blk, 0, stream>>>(S1, S2, f, kk0, multiL, multiR);

    for (int t = 0; t < 10; ++t) {
        const float kk = (t < 9) ? -exp2f(2.f * (float)(7 - t)) * L2E : 0.f;
        if (t == 0)
            k_B<true><<<gFat, blk, 0, stream>>>(S1, S2, f, remR, c, kk, multiR);
        else
            k_B<false><<<gFat, blk, 0, stream>>>(S1, S2, f, remR, c, kk, multiR);

        if (t < 8) {
            const float kp = kk * 0.25f;                 // = kk_{t+1}
            const float rsq = 1.f / sqrtf(-kp);
            if (t == 0)
                k_CA<1, true><<<gFat, blk, 0, stream>>>(S1, S2, f, c, remR, remL,
                                                        costrow, kp, rsq, multiL);
            else
                k_CA<1, false><<<gFat, blk, 0, stream>>>(S1, S2, f, c, remR, remL,
                                                         costrow, kp, rsq, multiL);
        } else if (t == 8) {
            const float kp = -0.25f * L2E;               // kk_8
            const float rsq = 1.f / sqrtf(0.25f * L2E);
            k_CA<2, false><<<gFat, blk, 0, stream>>>(S1, S2, f, c, remR, remL,
                                                     costrow, kp, rsq, multiL);
        } else {
            k_C9<<<gFat, blk, 0, stream>>>(S1, S2, f, c, costrow, out);
        }
    }
}